// Round 2
// baseline (421.056 us; speedup 1.0000x reference)
//
#include <hip/hip_runtime.h>
#include <math.h>

#define NB 16
#define NC 80
#define NA 21824
#define NM 1000
#define NHBINS 2048        // key>>51: sign(0)+exp8+mant4; scores<1 => prefix<=2031
#define CANDCAP 4096

// ws layout (bytes)
#define OFF_KEYS     0ul           // 16*21824*8   = 2,793,472
#define OFF_CLSV     2793472ul     // 16*21824*4   = 1,396,736
#define OFF_TOPSCORE 4190208ul     // 64,000
#define OFF_TOPCLS   4254208ul     // 64,000
#define OFF_TOPBOX   4318208ul     // 256,000 (16B aligned)
#define OFF_MAXB     4574208ul     // 64
#define OFF_MASK     4574272ul     // 16*16*1000*8 = 2,048,000 -> end 6,622,272
                                   // mask layout: [b][word][row] (row fast)

__device__ __forceinline__ float sigm(float x) { return 1.0f / (1.0f + expf(-x)); }

// ---------------- Kernel 1: per-anchor score/key/class (no histogram) ----------------
__global__ __launch_bounds__(256, 6) void k_score(
    const float* __restrict__ cls3, const float* __restrict__ cnt3,
    const float* __restrict__ cls4, const float* __restrict__ cnt4,
    const float* __restrict__ cls5, const float* __restrict__ cnt5,
    const float* __restrict__ cls6, const float* __restrict__ cnt6,
    const float* __restrict__ cls7, const float* __restrict__ cnt7,
    unsigned long long* __restrict__ keys,
    float* __restrict__ clsv)
{
    __shared__ float lm[4 * 64 * 4];
    __shared__ int   lam[4 * 64 * 4];
    __shared__ float cm[256];
    __shared__ int   cam[256];
    const int b = blockIdx.y;
    const int tid = threadIdx.x;
    const int a = tid & 63, s = tid >> 6;
    const int g4 = blockIdx.x * 64 + a;

    if (g4 < (NA >> 2)) {
        const int n = g4 << 2;
        const float* clsP; int off, logW;
        if      (n < 16384) { clsP = cls3; off = 0;     logW = 7; }
        else if (n < 20480) { clsP = cls4; off = 16384; logW = 6; }
        else if (n < 21504) { clsP = cls5; off = 20480; logW = 5; }
        else if (n < 21760) { clsP = cls6; off = 21504; logW = 4; }
        else                { clsP = cls7; off = 21760; logW = 3; }
        const int HW4 = 1 << (2 * logW - 2);
        const int l4 = (n - off) >> 2;
        const float4* cp = (const float4*)clsP + (size_t)b * NC * HW4 + l4;
        const int c0 = s * 20;
        float4 buf[4];
#pragma unroll
        for (int u = 0; u < 4; u++) buf[u] = cp[(size_t)(c0 + u) * HW4];
        float m[4] = { -3.402823466e+38f, -3.402823466e+38f, -3.402823466e+38f, -3.402823466e+38f };
        int am[4] = { c0, c0, c0, c0 };
#pragma unroll
        for (int u = 0; u < 20; u++) {
            float4 vv = buf[u & 3];
            if (u + 4 < 20) buf[u & 3] = cp[(size_t)(c0 + u + 4) * HW4];
            const int c = c0 + u;
            if (vv.x > m[0]) { m[0] = vv.x; am[0] = c; }   // strict > keeps first max (np.argmax)
            if (vv.y > m[1]) { m[1] = vv.y; am[1] = c; }
            if (vv.z > m[2]) { m[2] = vv.z; am[2] = c; }
            if (vv.w > m[3]) { m[3] = vv.w; am[3] = c; }
        }
#pragma unroll
        for (int k = 0; k < 4; k++) { lm[tid * 4 + k] = m[k]; lam[tid * 4 + k] = am[k]; }
    }
    __syncthreads();
    if (tid < 64 && (blockIdx.x * 64 + tid) < (NA >> 2)) {
        float M[4]; int AM[4];
#pragma unroll
        for (int k = 0; k < 4; k++) { M[k] = lm[tid * 4 + k]; AM[k] = lam[tid * 4 + k]; }
        for (int s2 = 1; s2 < 4; s2++) {
#pragma unroll
            for (int k = 0; k < 4; k++) {
                float vv = lm[(s2 * 64 + tid) * 4 + k];
                if (vv > M[k]) { M[k] = vv; AM[k] = lam[(s2 * 64 + tid) * 4 + k]; }
            }
        }
#pragma unroll
        for (int k = 0; k < 4; k++) { cm[tid * 4 + k] = M[k]; cam[tid * 4 + k] = AM[k]; }
    }
    __syncthreads();
    const int n2 = blockIdx.x * 256 + tid;
    if (n2 < NA) {
        const float* cntP; int off, logW;
        if      (n2 < 16384) { cntP = cnt3; off = 0;     logW = 7; }
        else if (n2 < 20480) { cntP = cnt4; off = 16384; logW = 6; }
        else if (n2 < 21504) { cntP = cnt5; off = 20480; logW = 5; }
        else if (n2 < 21760) { cntP = cnt6; off = 21504; logW = 4; }
        else                 { cntP = cnt7; off = 21760; logW = 3; }
        const int HW = 1 << (2 * logW);
        const int local = n2 - off;
        float cn = cntP[(size_t)b * HW + local];
        float M = cm[tid]; int AM = cam[tid];
        float sc = sqrtf(sigm(M) * sigm(cn));
        unsigned long long key = ((unsigned long long)__float_as_uint(sc) << 32)
                               | (unsigned int)(~(unsigned int)n2);
        keys[(size_t)b * NA + n2] = key;
        clsv[(size_t)b * NA + n2] = (float)(AM + 1);
    }
}

// ---------------- Kernel 2: per-batch fused hist + boundary + radix-compact + exact rank ----------------
// One block per batch image. Histogram lives in LDS (no global hist, no memset, no global atomics).
// Candidates are scattered into bin-sorted LDS order so exact rank = off[bin] + within-segment count
// (segments average ~2 entries).
__global__ __launch_bounds__(256) void k_mid(
    const unsigned long long* __restrict__ keys, const float* __restrict__ clsv,
    const float* __restrict__ reg3, const float* __restrict__ reg4, const float* __restrict__ reg5,
    const float* __restrict__ reg6, const float* __restrict__ reg7,
    float* __restrict__ topscore, float* __restrict__ topcls,
    float4* __restrict__ topbox, float* __restrict__ maxb)
{
    __shared__ unsigned int sh_hist[NHBINS];    // 8 KB
    __shared__ unsigned int sh_cur[NHBINS];     // 8 KB
    __shared__ unsigned int sh_off[NHBINS];     // 8 KB  (# keys in strictly higher bins)
    __shared__ unsigned long long scand[CANDCAP]; // 32 KB, bin-sorted candidates
    __shared__ int part1[256];
    __shared__ int part2[8];
    __shared__ int sBoundary;
    __shared__ float redmax[256];

    const int b = blockIdx.x;
    const int tid = threadIdx.x;
    const unsigned long long* kb = keys + (size_t)b * NA;
    const ulonglong2* k2 = (const ulonglong2*)kb;   // NA even, 16B-aligned

    for (int i = tid; i < NHBINS; i += 256) { sh_hist[i] = 0u; sh_cur[i] = 0u; }
    __syncthreads();

    // pass 1: histogram of key>>51
    for (int i = tid; i < NA / 2; i += 256) {
        ulonglong2 v = k2[i];
        atomicAdd(&sh_hist[(unsigned int)(v.x >> 51)], 1u);
        atomicAdd(&sh_hist[(unsigned int)(v.y >> 51)], 1u);
    }
    __syncthreads();

    // partial sums: part1[t] = bins [8t, 8t+8), part2[g] = bins [256g, 256g+256)
    { int s = 0; for (int i = 0; i < 8; i++) s += (int)sh_hist[tid * 8 + i]; part1[tid] = s; }
    __syncthreads();
    if (tid < 8) { int s2 = 0; for (int t = 0; t < 32; t++) s2 += part1[tid * 32 + t]; part2[tid] = s2; }
    __syncthreads();

    // boundary bin (largest bin s.t. count of keys in bins >= bin is >= NM)
    if (tid == 0) {
        int acc = 0, sc;
        for (sc = 7; sc > 0; sc--) { if (acc + part2[sc] >= NM) break; acc += part2[sc]; }
        int t;
        for (t = sc * 32 + 31; t > sc * 32; t--) { if (acc + part1[t] >= NM) break; acc += part1[t]; }
        int bin;
        for (bin = t * 8 + 7; bin > t * 8; bin--) { if (acc + (int)sh_hist[bin] >= NM) break; acc += (int)sh_hist[bin]; }
        sBoundary = bin;
    }
    // exclusive-from-top prefix: sh_off[bin] = # keys with bin' > bin  (runs concurrently with tid0 scan)
    {
        const int g = tid >> 5;
        int acc = 0;
        for (int q = g + 1; q < 8; q++) acc += part2[q];
        for (int t2 = (g << 5) + 31; t2 > tid; t2--) acc += part1[t2];
        int run = acc;
        for (int k = 7; k >= 0; k--) { sh_off[tid * 8 + k] = (unsigned int)run; run += (int)sh_hist[tid * 8 + k]; }
    }
    __syncthreads();

    const unsigned int boundary = (unsigned int)sBoundary;
    int cnt = (int)(sh_off[boundary] + sh_hist[boundary]);
    if (cnt > CANDCAP) cnt = CANDCAP;

    // pass 2: scatter candidates into bin-sorted order
    for (int i = tid; i < NA / 2; i += 256) {
        ulonglong2 v = k2[i];
        unsigned int b0 = (unsigned int)(v.x >> 51);
        if (b0 >= boundary) { unsigned int p = sh_off[b0] + atomicAdd(&sh_cur[b0], 1u); if (p < CANDCAP) scand[p] = v.x; }
        unsigned int b1 = (unsigned int)(v.y >> 51);
        if (b1 >= boundary) { unsigned int p = sh_off[b1] + atomicAdd(&sh_cur[b1], 1u); if (p < CANDCAP) scand[p] = v.y; }
    }
    __syncthreads();

    // rank + decode + write tops
    float mymax = -3.402823466e+38f;
    for (int idx = tid; idx < cnt; idx += 256) {
        const unsigned long long key = scand[idx];
        const unsigned int bin = (unsigned int)(key >> 51);
        int seg0 = (int)sh_off[bin];
        int seg1 = seg0 + (int)sh_hist[bin]; if (seg1 > cnt) seg1 = cnt;
        int rank = seg0;
        for (int j = seg0; j < seg1; j++) rank += (scand[j] > key);
        if (rank < NM) {
            const unsigned int ai = ~(unsigned int)key;
            const float* regP; int lvloff, W, logW, st;
            if      (ai < 16384) { regP = reg3; lvloff = 0;     W = 128; logW = 7; st = 8;   }
            else if (ai < 20480) { regP = reg4; lvloff = 16384; W = 64;  logW = 6; st = 16;  }
            else if (ai < 21504) { regP = reg5; lvloff = 20480; W = 32;  logW = 5; st = 32;  }
            else if (ai < 21760) { regP = reg6; lvloff = 21504; W = 16;  logW = 4; st = 64;  }
            else                 { regP = reg7; lvloff = 21760; W = 8;   logW = 3; st = 128; }
            const int local = (int)ai - lvloff;
            const int HW = 1 << (2 * logW);
            const float* rp = regP + (size_t)b * 4 * HW + local;
            float r0 = rp[0], r1 = rp[HW], r2 = rp[2 * HW], r3 = rp[3 * HW];
            float cv = clsv[(size_t)b * NA + ai];
            const float hs = (float)(st >> 1);
            float cx = (float)((local & (W - 1)) * st) + hs;
            float cy = (float)((local >> logW) * st) + hs;
            float4 bxv = make_float4(cx - r0, cy - r1, cx + r2, cy + r3);
            topscore[b * NM + rank] = __uint_as_float((unsigned int)(key >> 32));
            topcls[b * NM + rank] = cv;
            topbox[b * NM + rank] = bxv;
            mymax = fmaxf(mymax, fmaxf(fmaxf(bxv.x, bxv.y), fmaxf(bxv.z, bxv.w)));
        }
    }
    redmax[tid] = mymax;
    __syncthreads();
    for (int sgap = 128; sgap > 0; sgap >>= 1) {
        if (tid < sgap) redmax[tid] = fmaxf(redmax[tid], redmax[tid + sgap]);
        __syncthreads();
    }
    if (tid == 0) maxb[b] = __fadd_rn(redmax[0], 1.0f);   // max(boxes)+1.0, exact rn like reference
}

// ---------------- Kernel 3: suppression bitmask, layout mask[b][word][row] ----------------
// 1008 blocks: IoU build is compute-heavy (~8M IoUs total) and must stay wide.
__global__ __launch_bounds__(256) void k_iou(
    const float4* __restrict__ topbox, const float* __restrict__ topcls,
    const float* __restrict__ maxb, unsigned long long* __restrict__ maskArr)
{
    __shared__ float4 sB[NM];
    __shared__ float sA[NM];
    const int b = blockIdx.y;
    const int tid = threadIdx.x;
    const float mp1 = maxb[b];
    for (int r = tid; r < NM; r += 256) {
        float4 f = topbox[b * NM + r];
        float off = __fmul_rn(topcls[b * NM + r], mp1);
        f.x = __fadd_rn(f.x, off); f.y = __fadd_rn(f.y, off);
        f.z = __fadd_rn(f.z, off); f.w = __fadd_rn(f.w, off);
        sB[r] = f;
        sA[r] = __fmul_rn(__fadd_rn(__fsub_rn(f.z, f.x), 1.0f),
                          __fadd_rn(__fsub_rn(f.w, f.y), 1.0f));
    }
    __syncthreads();
    int task = blockIdx.x * 256 + tid;
    if (task >= NM * 16) return;
    int w = task / NM, i = task - w * NM;
    float4 bi = sB[i]; float ai = sA[i];
    unsigned long long bits = 0ULL;
    int j0 = w << 6;
    int jstart = (j0 > i + 1) ? j0 : i + 1;
    int jend = (j0 + 64 < NM) ? j0 + 64 : NM;
    for (int j = jstart; j < jend; j++) {
        float4 bj = sB[j];
        float xx1 = fmaxf(bi.x, bj.x);
        float yy1 = fmaxf(bi.y, bj.y);
        float xx2 = fminf(bi.z, bj.z);
        float yy2 = fminf(bi.w, bj.w);
        float iw = fmaxf(__fsub_rn(xx2, xx1), 0.0f);
        float ih = fmaxf(__fsub_rn(yy2, yy1), 0.0f);
        float inter = __fmul_rn(iw, ih);
        float denom = __fsub_rn(__fadd_rn(ai, sA[j]), inter);
        float iou = inter / denom;
        if (iou > 0.6f) bits |= (1ULL << (j - j0));
    }
    maskArr[((size_t)b * 16 + w) * NM + i] = bits;
}

// ---------------- Kernel 4: LDS-resident word-serial sweep + masked output ----------------
__global__ __launch_bounds__(256) void k_nms_sweep(
    const unsigned long long* __restrict__ maskArr,
    const float* __restrict__ topscore, const float* __restrict__ topcls,
    const float4* __restrict__ topbox, float* __restrict__ out)
{
    __shared__ unsigned long long smask[16 * NM];   // 125 KB, [word][row]
    __shared__ unsigned long long lremv[16];
    const int b = blockIdx.x;
    const int tid = threadIdx.x;
    const int j = tid & 63, q = tid >> 6;
    const unsigned long long* gmask = maskArr + (size_t)b * (16 * NM);

    {
        const ulonglong2* src = (const ulonglong2*)gmask;
        ulonglong2* dst = (ulonglong2*)smask;
        for (int idx = tid; idx < 8 * NM; idx += 256) dst[idx] = src[idx];
    }
    if (tid < 16) lremv[tid] = 0ULL;
    __syncthreads();
    for (int r = tid; r < NM; r += 256) {
        float s = topscore[b * NM + r];
        if (!(s >= 0.05f)) atomicOr(&lremv[r >> 6], 1ULL << (r & 63));
    }

    for (int w = 0; w < 16; w++) {
        __syncthreads();   // prior word's cross-word atomics + seeds visible
        const int row = w * 64 + j;
        unsigned long long D = (row < NM) ? smask[w * NM + row] : 0ULL;
        unsigned int dlo = (unsigned int)D, dhi = (unsigned int)(D >> 32);
        unsigned long long sv = lremv[w];
        unsigned int slo = __builtin_amdgcn_readfirstlane((unsigned int)sv);
        unsigned int shi = __builtin_amdgcn_readfirstlane((unsigned int)(sv >> 32));
        unsigned long long s = ((unsigned long long)shi << 32) | slo;
#pragma unroll
        for (int bb = 0; bb < 64; bb++) {
            unsigned int rlo = __builtin_amdgcn_readlane(dlo, bb);
            unsigned int rhi = __builtin_amdgcn_readlane(dhi, bb);
            unsigned long long rowv = ((unsigned long long)rhi << 32) | rlo;
            unsigned long long t = s | rowv;
            s = ((s >> bb) & 1ULL) ? s : t;
        }
        if (tid == 0) lremv[w] = s;
        const unsigned long long kw = ~s;
        if ((kw >> j) & 1ULL) {
            for (int k = w + 1 + q; k < 16; k += 4) {
                unsigned long long v = (row < NM) ? smask[k * NM + row] : 0ULL;
                if (v) atomicOr(&lremv[k], v);
            }
        }
    }
    __syncthreads();

    for (int r = tid; r < NM; r += 256) {
        bool keep = !((lremv[r >> 6] >> (r & 63)) & 1ULL);
        float kf = keep ? 1.0f : 0.0f;
        out[b * NM + r] = topscore[b * NM + r] * kf;
        out[NB * NM + b * NM + r] = topcls[b * NM + r] * kf;
        float4 bx = topbox[b * NM + r];
        ((float4*)(out + 2 * NB * NM))[b * NM + r] = make_float4(bx.x * kf, bx.y * kf, bx.z * kf, bx.w * kf);
    }
}

extern "C" void kernel_launch(void* const* d_in, const int* in_sizes, int n_in,
                              void* d_out, int out_size, void* d_ws, size_t ws_size,
                              hipStream_t stream) {
    const float* cls3 = (const float*)d_in[0];
    const float* cnt3 = (const float*)d_in[1];
    const float* reg3 = (const float*)d_in[2];
    const float* cls4 = (const float*)d_in[3];
    const float* cnt4 = (const float*)d_in[4];
    const float* reg4 = (const float*)d_in[5];
    const float* cls5 = (const float*)d_in[6];
    const float* cnt5 = (const float*)d_in[7];
    const float* reg5 = (const float*)d_in[8];
    const float* cls6 = (const float*)d_in[9];
    const float* cnt6 = (const float*)d_in[10];
    const float* reg6 = (const float*)d_in[11];
    const float* cls7 = (const float*)d_in[12];
    const float* cnt7 = (const float*)d_in[13];
    const float* reg7 = (const float*)d_in[14];

    char* ws = (char*)d_ws;
    unsigned long long* keys   = (unsigned long long*)(ws + OFF_KEYS);
    float*              clsv   = (float*)(ws + OFF_CLSV);
    float*              topsc  = (float*)(ws + OFF_TOPSCORE);
    float*              topcl  = (float*)(ws + OFF_TOPCLS);
    float4*             topbx  = (float4*)(ws + OFF_TOPBOX);
    float*              maxbF  = (float*)(ws + OFF_MAXB);
    unsigned long long* maskA  = (unsigned long long*)(ws + OFF_MASK);

    // no memset needed anymore: histogram/compact/rank state is all LDS-local in k_mid,
    // maxb is a plain per-batch store (no atomics on poisoned memory)

    dim3 g1(86, NB);   // 86*64 anchor-quads >= 5456
    k_score<<<g1, 256, 0, stream>>>(cls3, cnt3, cls4, cnt4, cls5, cnt5,
                                    cls6, cnt6, cls7, cnt7,
                                    keys, clsv);
    k_mid<<<dim3(NB), 256, 0, stream>>>(keys, clsv, reg3, reg4, reg5, reg6, reg7,
                                        topsc, topcl, topbx, maxbF);
    dim3 g4(63, NB);
    k_iou<<<g4, 256, 0, stream>>>(topbx, topcl, maxbF, maskA);
    k_nms_sweep<<<NB, 256, 0, stream>>>(maskA, topsc, topcl, topbx, (float*)d_out);
}

// Round 4
// 297.170 us; speedup vs baseline: 1.4169x; 1.4169x over previous
//
#include <hip/hip_runtime.h>
#include <math.h>

#define NB 16
#define NC 80
#define NA 21824
#define NM 1000
#define NHBINS 2048        // key>>51: sign(0)+exp8+mant4; scores<1 => prefix<=2031
#define CANDCAP 4096

// ws layout (bytes)
#define OFF_KEYS     0ul           // 16*21824*8   = 2,793,472
#define OFF_CLSV     2793472ul     // 16*21824*4   = 1,396,736
#define OFF_TOPSCORE 4190208ul     // 64,000
#define OFF_TOPCLS   4254208ul     // 64,000
#define OFF_TOPBOX   4318208ul     // 256,000 (16B aligned)
#define OFF_MAXB     4574208ul     // 64
#define OFF_MASK     4574272ul     // 16*16*1000*8 = 2,048,000 -> end 6,622,272
                                   // mask layout: [b][word][row] (row fast)

__device__ __forceinline__ float sigm(float x) { return 1.0f / (1.0f + expf(-x)); }

// ---------------- Kernel 1: per-anchor score/key/class (no histogram) ----------------
__global__ __launch_bounds__(256, 6) void k_score(
    const float* __restrict__ cls3, const float* __restrict__ cnt3,
    const float* __restrict__ cls4, const float* __restrict__ cnt4,
    const float* __restrict__ cls5, const float* __restrict__ cnt5,
    const float* __restrict__ cls6, const float* __restrict__ cnt6,
    const float* __restrict__ cls7, const float* __restrict__ cnt7,
    unsigned long long* __restrict__ keys,
    float* __restrict__ clsv)
{
    __shared__ float lm[4 * 64 * 4];
    __shared__ int   lam[4 * 64 * 4];
    __shared__ float cm[256];
    __shared__ int   cam[256];
    const int b = blockIdx.y;
    const int tid = threadIdx.x;
    const int a = tid & 63, s = tid >> 6;
    const int g4 = blockIdx.x * 64 + a;

    if (g4 < (NA >> 2)) {
        const int n = g4 << 2;
        const float* clsP; int off, logW;
        if      (n < 16384) { clsP = cls3; off = 0;     logW = 7; }
        else if (n < 20480) { clsP = cls4; off = 16384; logW = 6; }
        else if (n < 21504) { clsP = cls5; off = 20480; logW = 5; }
        else if (n < 21760) { clsP = cls6; off = 21504; logW = 4; }
        else                { clsP = cls7; off = 21760; logW = 3; }
        const int HW4 = 1 << (2 * logW - 2);
        const int l4 = (n - off) >> 2;
        const float4* cp = (const float4*)clsP + (size_t)b * NC * HW4 + l4;
        const int c0 = s * 20;
        float4 buf[4];
#pragma unroll
        for (int u = 0; u < 4; u++) buf[u] = cp[(size_t)(c0 + u) * HW4];
        float m[4] = { -3.402823466e+38f, -3.402823466e+38f, -3.402823466e+38f, -3.402823466e+38f };
        int am[4] = { c0, c0, c0, c0 };
#pragma unroll
        for (int u = 0; u < 20; u++) {
            float4 vv = buf[u & 3];
            if (u + 4 < 20) buf[u & 3] = cp[(size_t)(c0 + u + 4) * HW4];
            const int c = c0 + u;
            if (vv.x > m[0]) { m[0] = vv.x; am[0] = c; }   // strict > keeps first max (np.argmax)
            if (vv.y > m[1]) { m[1] = vv.y; am[1] = c; }
            if (vv.z > m[2]) { m[2] = vv.z; am[2] = c; }
            if (vv.w > m[3]) { m[3] = vv.w; am[3] = c; }
        }
#pragma unroll
        for (int k = 0; k < 4; k++) { lm[tid * 4 + k] = m[k]; lam[tid * 4 + k] = am[k]; }
    }
    __syncthreads();
    if (tid < 64 && (blockIdx.x * 64 + tid) < (NA >> 2)) {
        float M[4]; int AM[4];
#pragma unroll
        for (int k = 0; k < 4; k++) { M[k] = lm[tid * 4 + k]; AM[k] = lam[tid * 4 + k]; }
        for (int s2 = 1; s2 < 4; s2++) {
#pragma unroll
            for (int k = 0; k < 4; k++) {
                float vv = lm[(s2 * 64 + tid) * 4 + k];
                if (vv > M[k]) { M[k] = vv; AM[k] = lam[(s2 * 64 + tid) * 4 + k]; }
            }
        }
#pragma unroll
        for (int k = 0; k < 4; k++) { cm[tid * 4 + k] = M[k]; cam[tid * 4 + k] = AM[k]; }
    }
    __syncthreads();
    const int n2 = blockIdx.x * 256 + tid;
    if (n2 < NA) {
        const float* cntP; int off, logW;
        if      (n2 < 16384) { cntP = cnt3; off = 0;     logW = 7; }
        else if (n2 < 20480) { cntP = cnt4; off = 16384; logW = 6; }
        else if (n2 < 21504) { cntP = cnt5; off = 20480; logW = 5; }
        else if (n2 < 21760) { cntP = cnt6; off = 21504; logW = 4; }
        else                 { cntP = cnt7; off = 21760; logW = 3; }
        const int HW = 1 << (2 * logW);
        const int local = n2 - off;
        float cn = cntP[(size_t)b * HW + local];
        float M = cm[tid]; int AM = cam[tid];
        float sc = sqrtf(sigm(M) * sigm(cn));
        unsigned long long key = ((unsigned long long)__float_as_uint(sc) << 32)
                               | (unsigned int)(~(unsigned int)n2);
        keys[(size_t)b * NA + n2] = key;
        clsv[(size_t)b * NA + n2] = (float)(AM + 1);
    }
}

// ---------------- Kernel 2: per-batch fused hist + boundary + radix-compact + 2-level rank ----------
// One block per batch image. All state LDS-local. Level-1: 2048 bins on key>>51. The score
// distribution concentrates in a few mantissa bins, so ONLY the boundary bin can be large
// (bins above it sum to < NM by construction). Level-2: refine the boundary bin with the next
// 11 mantissa bits (key>>40 & 2047) and re-scatter it sub-bin-sorted into scand2, so every
// rank scan is over a tiny segment. This removes the O(cnt * segment) serial scan that made
// the previous version 197 us.
__global__ __launch_bounds__(256) void k_mid(
    const unsigned long long* __restrict__ keys, const float* __restrict__ clsv,
    const float* __restrict__ reg3, const float* __restrict__ reg4, const float* __restrict__ reg5,
    const float* __restrict__ reg6, const float* __restrict__ reg7,
    float* __restrict__ topscore, float* __restrict__ topcls,
    float4* __restrict__ topbox, float* __restrict__ maxb)
{
    __shared__ unsigned int sh_hist[NHBINS];      // 8 KB  level-1 histogram
    __shared__ unsigned int sh_cur[NHBINS];       // 8 KB  level-1 scatter counters
    __shared__ unsigned int sh_off[NHBINS];       // 8 KB  # keys in strictly higher bins
    __shared__ unsigned int sh_subh[NHBINS];      // 8 KB  level-2 histogram (boundary bin)
    __shared__ unsigned int sh_subo[NHBINS];      // 8 KB  level-2 descending prefix
    __shared__ unsigned int sh_subc[NHBINS];      // 8 KB  level-2 scatter counters
    __shared__ unsigned long long scand[CANDCAP]; // 32 KB bin-sorted candidates
    __shared__ unsigned long long scand2[CANDCAP];// 32 KB boundary segment, sub-bin-sorted
    __shared__ int part1[256];
    __shared__ int part2[8];
    __shared__ int sBoundary;
    __shared__ float redmax[256];

    const int b = blockIdx.x;
    const int tid = threadIdx.x;
    const unsigned long long* kb = keys + (size_t)b * NA;
    const ulonglong2* k2 = (const ulonglong2*)kb;   // NA even, 16B-aligned

    for (int i = tid; i < NHBINS; i += 256) {
        sh_hist[i] = 0u; sh_cur[i] = 0u; sh_subh[i] = 0u; sh_subc[i] = 0u;
    }
    __syncthreads();

    // ---- pass 1: level-1 histogram of key>>51 ----
    for (int i = tid; i < NA / 2; i += 256) {
        ulonglong2 v = k2[i];
        atomicAdd(&sh_hist[(unsigned int)(v.x >> 51)], 1u);
        atomicAdd(&sh_hist[(unsigned int)(v.y >> 51)], 1u);
    }
    __syncthreads();

    // partial sums: part1[t] = bins [8t, 8t+8), part2[g] = bins [256g, 256g+256)
    { int s = 0; for (int i = 0; i < 8; i++) s += (int)sh_hist[tid * 8 + i]; part1[tid] = s; }
    __syncthreads();
    if (tid < 8) { int s2 = 0; for (int t = 0; t < 32; t++) s2 += part1[tid * 32 + t]; part2[tid] = s2; }
    __syncthreads();

    // boundary bin (largest bin s.t. count of keys in bins >= bin is >= NM)
    if (tid == 0) {
        int acc = 0, sc;
        for (sc = 7; sc > 0; sc--) { if (acc + part2[sc] >= NM) break; acc += part2[sc]; }
        int t;
        for (t = sc * 32 + 31; t > sc * 32; t--) { if (acc + part1[t] >= NM) break; acc += part1[t]; }
        int bin;
        for (bin = t * 8 + 7; bin > t * 8; bin--) { if (acc + (int)sh_hist[bin] >= NM) break; acc += (int)sh_hist[bin]; }
        sBoundary = bin;
    }
    // exclusive-from-top prefix: sh_off[bin] = # keys with bin' > bin  (concurrent with tid0 scan)
    {
        const int g = tid >> 5;
        int acc = 0;
        for (int q = g + 1; q < 8; q++) acc += part2[q];
        for (int t2 = (g << 5) + 31; t2 > tid; t2--) acc += part1[t2];
        int run = acc;
        for (int k = 7; k >= 0; k--) { sh_off[tid * 8 + k] = (unsigned int)run; run += (int)sh_hist[tid * 8 + k]; }
    }
    __syncthreads();

    const unsigned int boundary = (unsigned int)sBoundary;
    int total = (int)(sh_off[boundary] + sh_hist[boundary]);
    int cnt = (total > CANDCAP) ? CANDCAP : total;
    const int s0 = (int)sh_off[boundary];   // start of boundary segment (< NM <= cnt)
    const int Lb = cnt - s0;                // boundary segment size as stored (>= 1)

    // ---- pass 2: scatter candidates into level-1 bin-sorted order ----
    for (int i = tid; i < NA / 2; i += 256) {
        ulonglong2 v = k2[i];
        unsigned int b0 = (unsigned int)(v.x >> 51);
        if (b0 >= boundary) { unsigned int p = sh_off[b0] + atomicAdd(&sh_cur[b0], 1u); if (p < CANDCAP) scand[p] = v.x; }
        unsigned int b1 = (unsigned int)(v.y >> 51);
        if (b1 >= boundary) { unsigned int p = sh_off[b1] + atomicAdd(&sh_cur[b1], 1u); if (p < CANDCAP) scand[p] = v.y; }
    }
    __syncthreads();

    // ---- level-2: sub-histogram of the boundary segment on bits [50:40] ----
    for (int k = tid; k < Lb; k += 256)
        atomicAdd(&sh_subh[(unsigned int)(scand[s0 + k] >> 40) & 2047u], 1u);
    __syncthreads();

    // descending prefix over sub-bins (reuse part1/part2)
    { int s = 0; for (int i = 0; i < 8; i++) s += (int)sh_subh[tid * 8 + i]; part1[tid] = s; }
    __syncthreads();
    if (tid < 8) { int s2 = 0; for (int t = 0; t < 32; t++) s2 += part1[tid * 32 + t]; part2[tid] = s2; }
    __syncthreads();
    {
        const int g = tid >> 5;
        int acc = 0;
        for (int q = g + 1; q < 8; q++) acc += part2[q];
        for (int t2 = (g << 5) + 31; t2 > tid; t2--) acc += part1[t2];
        int run = acc;
        for (int k = 7; k >= 0; k--) { sh_subo[tid * 8 + k] = (unsigned int)run; run += (int)sh_subh[tid * 8 + k]; }
    }
    __syncthreads();

    // re-scatter boundary segment into sub-bin-sorted order (scand -> scand2)
    for (int k = tid; k < Lb; k += 256) {
        unsigned long long v = scand[s0 + k];
        unsigned int sb = (unsigned int)(v >> 40) & 2047u;
        unsigned int p = sh_subo[sb] + atomicAdd(&sh_subc[sb], 1u);
        scand2[p] = v;   // p < Lb <= CANDCAP by construction
    }
    __syncthreads();

    // ---- rank + decode + write tops ----
    float mymax = -3.402823466e+38f;
    for (int idx = tid; idx < cnt; idx += 256) {
        const unsigned long long key = (idx < s0) ? scand[idx] : scand2[idx - s0];
        const unsigned int bin = (unsigned int)(key >> 51);
        int rank;
        if (bin > boundary) {
            // segments above boundary sum to < NM -> small scans
            int g0 = (int)sh_off[bin];
            int g1 = g0 + (int)sh_hist[bin];        // <= s0
            rank = g0;
            for (int j = g0; j < g1; j++) rank += (scand[j] > key);
        } else {
            // boundary bin: tiny sub-segment in scand2
            unsigned int sb = (unsigned int)(key >> 40) & 2047u;
            int t0 = (int)sh_subo[sb];
            int t1 = t0 + (int)sh_subh[sb];         // <= Lb
            rank = s0 + t0;
            for (int j = t0; j < t1; j++) rank += (scand2[j] > key);
        }
        if (rank < NM) {
            const unsigned int ai = ~(unsigned int)key;
            const float* regP; int lvloff, W, logW, st;
            if      (ai < 16384) { regP = reg3; lvloff = 0;     W = 128; logW = 7; st = 8;   }
            else if (ai < 20480) { regP = reg4; lvloff = 16384; W = 64;  logW = 6; st = 16;  }
            else if (ai < 21504) { regP = reg5; lvloff = 20480; W = 32;  logW = 5; st = 32;  }
            else if (ai < 21760) { regP = reg6; lvloff = 21504; W = 16;  logW = 4; st = 64;  }
            else                 { regP = reg7; lvloff = 21760; W = 8;   logW = 3; st = 128; }
            const int local = (int)ai - lvloff;
            const int HW = 1 << (2 * logW);
            const float* rp = regP + (size_t)b * 4 * HW + local;
            float r0 = rp[0], r1 = rp[HW], r2 = rp[2 * HW], r3 = rp[3 * HW];
            float cv = clsv[(size_t)b * NA + ai];
            const float hs = (float)(st >> 1);
            float cx = (float)((local & (W - 1)) * st) + hs;
            float cy = (float)((local >> logW) * st) + hs;
            float4 bxv = make_float4(cx - r0, cy - r1, cx + r2, cy + r3);
            topscore[b * NM + rank] = __uint_as_float((unsigned int)(key >> 32));
            topcls[b * NM + rank] = cv;
            topbox[b * NM + rank] = bxv;
            mymax = fmaxf(mymax, fmaxf(fmaxf(bxv.x, bxv.y), fmaxf(bxv.z, bxv.w)));
        }
    }
    redmax[tid] = mymax;
    __syncthreads();
    for (int sgap = 128; sgap > 0; sgap >>= 1) {
        if (tid < sgap) redmax[tid] = fmaxf(redmax[tid], redmax[tid + sgap]);
        __syncthreads();
    }
    if (tid == 0) maxb[b] = __fadd_rn(redmax[0], 1.0f);   // max(boxes)+1.0, exact rn like reference
}

// ---------------- Kernel 3: suppression bitmask, layout mask[b][word][row] ----------------
// 1008 blocks: IoU build is compute-heavy (~8M IoUs total) and must stay wide.
__global__ __launch_bounds__(256) void k_iou(
    const float4* __restrict__ topbox, const float* __restrict__ topcls,
    const float* __restrict__ maxb, unsigned long long* __restrict__ maskArr)
{
    __shared__ float4 sB[NM];
    __shared__ float sA[NM];
    const int b = blockIdx.y;
    const int tid = threadIdx.x;
    const float mp1 = maxb[b];
    for (int r = tid; r < NM; r += 256) {
        float4 f = topbox[b * NM + r];
        float off = __fmul_rn(topcls[b * NM + r], mp1);
        f.x = __fadd_rn(f.x, off); f.y = __fadd_rn(f.y, off);
        f.z = __fadd_rn(f.z, off); f.w = __fadd_rn(f.w, off);
        sB[r] = f;
        sA[r] = __fmul_rn(__fadd_rn(__fsub_rn(f.z, f.x), 1.0f),
                          __fadd_rn(__fsub_rn(f.w, f.y), 1.0f));
    }
    __syncthreads();
    int task = blockIdx.x * 256 + tid;
    if (task >= NM * 16) return;
    int w = task / NM, i = task - w * NM;
    float4 bi = sB[i]; float ai = sA[i];
    unsigned long long bits = 0ULL;
    int j0 = w << 6;
    int jstart = (j0 > i + 1) ? j0 : i + 1;
    int jend = (j0 + 64 < NM) ? j0 + 64 : NM;
    for (int j = jstart; j < jend; j++) {
        float4 bj = sB[j];
        float xx1 = fmaxf(bi.x, bj.x);
        float yy1 = fmaxf(bi.y, bj.y);
        float xx2 = fminf(bi.z, bj.z);
        float yy2 = fminf(bi.w, bj.w);
        float iw = fmaxf(__fsub_rn(xx2, xx1), 0.0f);
        float ih = fmaxf(__fsub_rn(yy2, yy1), 0.0f);
        float inter = __fmul_rn(iw, ih);
        float denom = __fsub_rn(__fadd_rn(ai, sA[j]), inter);
        float iou = inter / denom;
        if (iou > 0.6f) bits |= (1ULL << (j - j0));
    }
    maskArr[((size_t)b * 16 + w) * NM + i] = bits;
}

// ---------------- Kernel 4: LDS-resident word-serial sweep + masked output ----------------
__global__ __launch_bounds__(256) void k_nms_sweep(
    const unsigned long long* __restrict__ maskArr,
    const float* __restrict__ topscore, const float* __restrict__ topcls,
    const float4* __restrict__ topbox, float* __restrict__ out)
{
    __shared__ unsigned long long smask[16 * NM];   // 125 KB, [word][row]
    __shared__ unsigned long long lremv[16];
    const int b = blockIdx.x;
    const int tid = threadIdx.x;
    const int j = tid & 63, q = tid >> 6;
    const unsigned long long* gmask = maskArr + (size_t)b * (16 * NM);

    {
        const ulonglong2* src = (const ulonglong2*)gmask;
        ulonglong2* dst = (ulonglong2*)smask;
        for (int idx = tid; idx < 8 * NM; idx += 256) dst[idx] = src[idx];
    }
    if (tid < 16) lremv[tid] = 0ULL;
    __syncthreads();
    for (int r = tid; r < NM; r += 256) {
        float s = topscore[b * NM + r];
        if (!(s >= 0.05f)) atomicOr(&lremv[r >> 6], 1ULL << (r & 63));
    }

    for (int w = 0; w < 16; w++) {
        __syncthreads();   // prior word's cross-word atomics + seeds visible
        const int row = w * 64 + j;
        unsigned long long D = (row < NM) ? smask[w * NM + row] : 0ULL;
        unsigned int dlo = (unsigned int)D, dhi = (unsigned int)(D >> 32);
        unsigned long long sv = lremv[w];
        unsigned int slo = __builtin_amdgcn_readfirstlane((unsigned int)sv);
        unsigned int shi = __builtin_amdgcn_readfirstlane((unsigned int)(sv >> 32));
        unsigned long long s = ((unsigned long long)shi << 32) | slo;
#pragma unroll
        for (int bb = 0; bb < 64; bb++) {
            unsigned int rlo = __builtin_amdgcn_readlane(dlo, bb);
            unsigned int rhi = __builtin_amdgcn_readlane(dhi, bb);
            unsigned long long rowv = ((unsigned long long)rhi << 32) | rlo;
            unsigned long long t = s | rowv;
            s = ((s >> bb) & 1ULL) ? s : t;
        }
        if (tid == 0) lremv[w] = s;
        const unsigned long long kw = ~s;
        if ((kw >> j) & 1ULL) {
            for (int k = w + 1 + q; k < 16; k += 4) {
                unsigned long long v = (row < NM) ? smask[k * NM + row] : 0ULL;
                if (v) atomicOr(&lremv[k], v);
            }
        }
    }
    __syncthreads();

    for (int r = tid; r < NM; r += 256) {
        bool keep = !((lremv[r >> 6] >> (r & 63)) & 1ULL);
        float kf = keep ? 1.0f : 0.0f;
        out[b * NM + r] = topscore[b * NM + r] * kf;
        out[NB * NM + b * NM + r] = topcls[b * NM + r] * kf;
        float4 bx = topbox[b * NM + r];
        ((float4*)(out + 2 * NB * NM))[b * NM + r] = make_float4(bx.x * kf, bx.y * kf, bx.z * kf, bx.w * kf);
    }
}

extern "C" void kernel_launch(void* const* d_in, const int* in_sizes, int n_in,
                              void* d_out, int out_size, void* d_ws, size_t ws_size,
                              hipStream_t stream) {
    const float* cls3 = (const float*)d_in[0];
    const float* cnt3 = (const float*)d_in[1];
    const float* reg3 = (const float*)d_in[2];
    const float* cls4 = (const float*)d_in[3];
    const float* cnt4 = (const float*)d_in[4];
    const float* reg4 = (const float*)d_in[5];
    const float* cls5 = (const float*)d_in[6];
    const float* cnt5 = (const float*)d_in[7];
    const float* reg5 = (const float*)d_in[8];
    const float* cls6 = (const float*)d_in[9];
    const float* cnt6 = (const float*)d_in[10];
    const float* reg6 = (const float*)d_in[11];
    const float* cls7 = (const float*)d_in[12];
    const float* cnt7 = (const float*)d_in[13];
    const float* reg7 = (const float*)d_in[14];

    char* ws = (char*)d_ws;
    unsigned long long* keys   = (unsigned long long*)(ws + OFF_KEYS);
    float*              clsv   = (float*)(ws + OFF_CLSV);
    float*              topsc  = (float*)(ws + OFF_TOPSCORE);
    float*              topcl  = (float*)(ws + OFF_TOPCLS);
    float4*             topbx  = (float4*)(ws + OFF_TOPBOX);
    float*              maxbF  = (float*)(ws + OFF_MAXB);
    unsigned long long* maskA  = (unsigned long long*)(ws + OFF_MASK);

    dim3 g1(86, NB);   // 86*64 anchor-quads >= 5456
    k_score<<<g1, 256, 0, stream>>>(cls3, cnt3, cls4, cnt4, cls5, cnt5,
                                    cls6, cnt6, cls7, cnt7,
                                    keys, clsv);
    k_mid<<<dim3(NB), 256, 0, stream>>>(keys, clsv, reg3, reg4, reg5, reg6, reg7,
                                        topsc, topcl, topbx, maxbF);
    dim3 g4(63, NB);
    k_iou<<<g4, 256, 0, stream>>>(topbx, topcl, maxbF, maskA);
    k_nms_sweep<<<NB, 256, 0, stream>>>(maskA, topsc, topcl, topbx, (float*)d_out);
}

// Round 5
// 265.043 us; speedup vs baseline: 1.5886x; 1.1212x over previous
//
#include <hip/hip_runtime.h>
#include <math.h>

#define NB 16
#define NC 80
#define NA 21824
#define NM 1000
#define NHBINS 2048        // key>>51: sign(0)+exp8+mant4; scores<1 => prefix<=2031
#define CANDCAP 4096
#define BSZ 1024           // k_mid block size: 16 waves/CU

// ws layout (bytes)
#define OFF_KEYS     0ul           // 16*21824*8   = 2,793,472
#define OFF_CLSV     2793472ul     // 16*21824*4   = 1,396,736
#define OFF_TOPSCORE 4190208ul     // 64,000
#define OFF_TOPCLS   4254208ul     // 64,000
#define OFF_TOPBOX   4318208ul     // 256,000 (16B aligned)
#define OFF_MAXB     4574208ul     // 64
#define OFF_MASK     4574272ul     // 16*16*1000*8 = 2,048,000 -> end 6,622,272
                                   // mask layout: [b][word][row] (row fast)

__device__ __forceinline__ float sigm(float x) { return 1.0f / (1.0f + expf(-x)); }

// ---------------- Kernel 1: per-anchor score/key/class ----------------
__global__ __launch_bounds__(256, 6) void k_score(
    const float* __restrict__ cls3, const float* __restrict__ cnt3,
    const float* __restrict__ cls4, const float* __restrict__ cnt4,
    const float* __restrict__ cls5, const float* __restrict__ cnt5,
    const float* __restrict__ cls6, const float* __restrict__ cnt6,
    const float* __restrict__ cls7, const float* __restrict__ cnt7,
    unsigned long long* __restrict__ keys,
    float* __restrict__ clsv)
{
    __shared__ float lm[4 * 64 * 4];
    __shared__ int   lam[4 * 64 * 4];
    __shared__ float cm[256];
    __shared__ int   cam[256];
    const int b = blockIdx.y;
    const int tid = threadIdx.x;
    const int a = tid & 63, s = tid >> 6;
    const int g4 = blockIdx.x * 64 + a;

    if (g4 < (NA >> 2)) {
        const int n = g4 << 2;
        const float* clsP; int off, logW;
        if      (n < 16384) { clsP = cls3; off = 0;     logW = 7; }
        else if (n < 20480) { clsP = cls4; off = 16384; logW = 6; }
        else if (n < 21504) { clsP = cls5; off = 20480; logW = 5; }
        else if (n < 21760) { clsP = cls6; off = 21504; logW = 4; }
        else                { clsP = cls7; off = 21760; logW = 3; }
        const int HW4 = 1 << (2 * logW - 2);
        const int l4 = (n - off) >> 2;
        const float4* cp = (const float4*)clsP + (size_t)b * NC * HW4 + l4;
        const int c0 = s * 20;
        float4 buf[4];
#pragma unroll
        for (int u = 0; u < 4; u++) buf[u] = cp[(size_t)(c0 + u) * HW4];
        float m[4] = { -3.402823466e+38f, -3.402823466e+38f, -3.402823466e+38f, -3.402823466e+38f };
        int am[4] = { c0, c0, c0, c0 };
#pragma unroll
        for (int u = 0; u < 20; u++) {
            float4 vv = buf[u & 3];
            if (u + 4 < 20) buf[u & 3] = cp[(size_t)(c0 + u + 4) * HW4];
            const int c = c0 + u;
            if (vv.x > m[0]) { m[0] = vv.x; am[0] = c; }   // strict > keeps first max (np.argmax)
            if (vv.y > m[1]) { m[1] = vv.y; am[1] = c; }
            if (vv.z > m[2]) { m[2] = vv.z; am[2] = c; }
            if (vv.w > m[3]) { m[3] = vv.w; am[3] = c; }
        }
#pragma unroll
        for (int k = 0; k < 4; k++) { lm[tid * 4 + k] = m[k]; lam[tid * 4 + k] = am[k]; }
    }
    __syncthreads();
    if (tid < 64 && (blockIdx.x * 64 + tid) < (NA >> 2)) {
        float M[4]; int AM[4];
#pragma unroll
        for (int k = 0; k < 4; k++) { M[k] = lm[tid * 4 + k]; AM[k] = lam[tid * 4 + k]; }
        for (int s2 = 1; s2 < 4; s2++) {
#pragma unroll
            for (int k = 0; k < 4; k++) {
                float vv = lm[(s2 * 64 + tid) * 4 + k];
                if (vv > M[k]) { M[k] = vv; AM[k] = lam[(s2 * 64 + tid) * 4 + k]; }
            }
        }
#pragma unroll
        for (int k = 0; k < 4; k++) { cm[tid * 4 + k] = M[k]; cam[tid * 4 + k] = AM[k]; }
    }
    __syncthreads();
    const int n2 = blockIdx.x * 256 + tid;
    if (n2 < NA) {
        const float* cntP; int off, logW;
        if      (n2 < 16384) { cntP = cnt3; off = 0;     logW = 7; }
        else if (n2 < 20480) { cntP = cnt4; off = 16384; logW = 6; }
        else if (n2 < 21504) { cntP = cnt5; off = 20480; logW = 5; }
        else if (n2 < 21760) { cntP = cnt6; off = 21504; logW = 4; }
        else                 { cntP = cnt7; off = 21760; logW = 3; }
        const int HW = 1 << (2 * logW);
        const int local = n2 - off;
        float cn = cntP[(size_t)b * HW + local];
        float M = cm[tid]; int AM = cam[tid];
        float sc = sqrtf(sigm(M) * sigm(cn));
        unsigned long long key = ((unsigned long long)__float_as_uint(sc) << 32)
                               | (unsigned int)(~(unsigned int)n2);
        keys[(size_t)b * NA + n2] = key;
        clsv[(size_t)b * NA + n2] = (float)(AM + 1);
    }
}

// ---------------- Kernel 2: per-batch fused hist + boundary + 2-level radix rank (1024 thr) --------
// 3 passes over the (L2-resident) keys row. Boundary-bin keys NEVER go through a single
// scatter counter: bins > boundary (total < NM by construction) go to scand[NM]; the
// boundary bin is sub-histogrammed on bits [50:40] directly from global keys, then scattered
// sub-bin-sorted into scand2. Rank = descending prefix + tiny segment scan.
__global__ __launch_bounds__(BSZ) void k_mid(
    const unsigned long long* __restrict__ keys, const float* __restrict__ clsv,
    const float* __restrict__ reg3, const float* __restrict__ reg4, const float* __restrict__ reg5,
    const float* __restrict__ reg6, const float* __restrict__ reg7,
    float* __restrict__ topscore, float* __restrict__ topcls,
    float4* __restrict__ topbox, float* __restrict__ maxb)
{
    __shared__ unsigned int sh_hist[NHBINS];      // 8 KB  level-1 histogram
    __shared__ unsigned int sh_cur[NHBINS];       // 8 KB  scatter counters (bins > boundary only)
    __shared__ unsigned int sh_off[NHBINS];       // 8 KB  # keys in strictly higher bins
    __shared__ unsigned int sh_subh[NHBINS];      // 8 KB  level-2 histogram (boundary bin)
    __shared__ unsigned int sh_subo[NHBINS];      // 8 KB  level-2 descending prefix
    __shared__ unsigned int sh_subc[NHBINS];      // 8 KB  level-2 scatter counters
    __shared__ unsigned long long scand[NM];      // 8 KB  bins > boundary (sum < NM guaranteed)
    __shared__ unsigned long long scand2[CANDCAP];// 32 KB boundary bin, sub-bin-sorted
    __shared__ int part1[BSZ];                    // 4 KB
    __shared__ int part2[32];
    __shared__ int sBoundary;
    __shared__ float redmax[BSZ];                 // 4 KB

    const int b = blockIdx.x;
    const int tid = threadIdx.x;
    const ulonglong2* k2 = (const ulonglong2*)(keys + (size_t)b * NA);   // 16B-aligned

    for (int i = tid; i < NHBINS; i += BSZ) {
        sh_hist[i] = 0u; sh_cur[i] = 0u; sh_subh[i] = 0u; sh_subc[i] = 0u;
    }
    __syncthreads();

    // ---- pass 1: level-1 histogram of key>>51 ----
    for (int i = tid; i < NA / 2; i += BSZ) {
        ulonglong2 v = k2[i];
        atomicAdd(&sh_hist[(unsigned int)(v.x >> 51)], 1u);
        atomicAdd(&sh_hist[(unsigned int)(v.y >> 51)], 1u);
    }
    __syncthreads();

    // partial sums: part1[t] = bins [2t, 2t+2), part2[g] = bins [64g, 64g+64)
    part1[tid] = (int)sh_hist[2 * tid] + (int)sh_hist[2 * tid + 1];
    __syncthreads();
    if (tid < 32) { int s2 = 0; for (int t = 0; t < 32; t++) s2 += part1[tid * 32 + t]; part2[tid] = s2; }
    __syncthreads();

    // boundary bin (largest bin s.t. count of keys in bins >= bin is >= NM)
    if (tid == 0) {
        int acc = 0, g;
        for (g = 31; g > 0; g--) { if (acc + part2[g] >= NM) break; acc += part2[g]; }
        int t;
        for (t = g * 32 + 31; t > g * 32; t--) { if (acc + part1[t] >= NM) break; acc += part1[t]; }
        int bin = 2 * t + 1;
        if (acc + (int)sh_hist[bin] < NM) { acc += (int)sh_hist[bin]; bin = 2 * t; }
        sBoundary = bin;
    }
    // exclusive-from-top prefix: sh_off[bin] = # keys with bin' > bin
    {
        const int g = tid >> 5;
        int acc = 0;
        for (int q = g + 1; q < 32; q++) acc += part2[q];
        for (int t2 = (g << 5) + 31; t2 > tid; t2--) acc += part1[t2];
        sh_off[2 * tid + 1] = (unsigned int)acc;
        sh_off[2 * tid]     = (unsigned int)(acc + (int)sh_hist[2 * tid + 1]);
    }
    __syncthreads();

    const unsigned int boundary = (unsigned int)sBoundary;
    const int s0 = (int)sh_off[boundary];   // # keys above boundary, < NM by construction

    // ---- pass 2a: scatter bins>boundary to scand; build level-2 subhist for boundary bin ----
    for (int i = tid; i < NA / 2; i += BSZ) {
        ulonglong2 v = k2[i];
#pragma unroll
        for (int h = 0; h < 2; h++) {
            const unsigned long long kk = h ? v.y : v.x;
            const unsigned int bb = (unsigned int)(kk >> 51);
            if (bb > boundary) {
                unsigned int p = sh_off[bb] + atomicAdd(&sh_cur[bb], 1u);
                if (p < (unsigned int)NM) scand[p] = kk;      // p < s0 < NM always
            } else if (bb == boundary) {
                atomicAdd(&sh_subh[(unsigned int)(kk >> 40) & 2047u], 1u);
            }
        }
    }
    __syncthreads();

    // level-2 descending prefix over sub-bins
    part1[tid] = (int)sh_subh[2 * tid] + (int)sh_subh[2 * tid + 1];
    __syncthreads();
    if (tid < 32) { int s2 = 0; for (int t = 0; t < 32; t++) s2 += part1[tid * 32 + t]; part2[tid] = s2; }
    __syncthreads();
    {
        const int g = tid >> 5;
        int acc = 0;
        for (int q = g + 1; q < 32; q++) acc += part2[q];
        for (int t2 = (g << 5) + 31; t2 > tid; t2--) acc += part1[t2];
        sh_subo[2 * tid + 1] = (unsigned int)acc;
        sh_subo[2 * tid]     = (unsigned int)(acc + (int)sh_subh[2 * tid + 1]);
    }
    __syncthreads();

    // ---- pass 2b: scatter boundary-bin keys sub-bin-sorted into scand2 ----
    for (int i = tid; i < NA / 2; i += BSZ) {
        ulonglong2 v = k2[i];
#pragma unroll
        for (int h = 0; h < 2; h++) {
            const unsigned long long kk = h ? v.y : v.x;
            if ((unsigned int)(kk >> 51) == boundary) {
                unsigned int sb = (unsigned int)(kk >> 40) & 2047u;
                unsigned int p = sh_subo[sb] + atomicAdd(&sh_subc[sb], 1u);
                if (p < CANDCAP) scand2[p] = kk;
            }
        }
    }
    __syncthreads();

    // ---- rank + decode + write tops ----
    int Lbs = (int)sh_hist[boundary]; if (Lbs > CANDCAP) Lbs = CANDCAP;
    const int cnt = s0 + Lbs;
    float mymax = -3.402823466e+38f;
    for (int idx = tid; idx < cnt; idx += BSZ) {
        unsigned long long key; int rank;
        if (idx < s0) {
            key = scand[idx];
            const unsigned int bin = (unsigned int)(key >> 51);
            int g0 = (int)sh_off[bin];
            int g1 = g0 + (int)sh_hist[bin]; if (g1 > s0) g1 = s0;
            rank = g0;
            for (int j = g0; j < g1; j++) rank += (scand[j] > key);
        } else {
            key = scand2[idx - s0];
            const unsigned int sb = (unsigned int)(key >> 40) & 2047u;
            int t0 = (int)sh_subo[sb];
            int t1 = t0 + (int)sh_subh[sb]; if (t1 > Lbs) t1 = Lbs;
            rank = s0 + t0;
            for (int j = t0; j < t1; j++) rank += (scand2[j] > key);
        }
        if (rank < NM) {
            const unsigned int ai = ~(unsigned int)key;
            const float* regP; int lvloff, W, logW, st;
            if      (ai < 16384) { regP = reg3; lvloff = 0;     W = 128; logW = 7; st = 8;   }
            else if (ai < 20480) { regP = reg4; lvloff = 16384; W = 64;  logW = 6; st = 16;  }
            else if (ai < 21504) { regP = reg5; lvloff = 20480; W = 32;  logW = 5; st = 32;  }
            else if (ai < 21760) { regP = reg6; lvloff = 21504; W = 16;  logW = 4; st = 64;  }
            else                 { regP = reg7; lvloff = 21760; W = 8;   logW = 3; st = 128; }
            const int local = (int)ai - lvloff;
            const int HW = 1 << (2 * logW);
            const float* rp = regP + (size_t)b * 4 * HW + local;
            float r0 = rp[0], r1 = rp[HW], r2 = rp[2 * HW], r3 = rp[3 * HW];
            float cv = clsv[(size_t)b * NA + ai];
            const float hs = (float)(st >> 1);
            float cx = (float)((local & (W - 1)) * st) + hs;
            float cy = (float)((local >> logW) * st) + hs;
            float4 bxv = make_float4(cx - r0, cy - r1, cx + r2, cy + r3);
            topscore[b * NM + rank] = __uint_as_float((unsigned int)(key >> 32));
            topcls[b * NM + rank] = cv;
            topbox[b * NM + rank] = bxv;
            mymax = fmaxf(mymax, fmaxf(fmaxf(bxv.x, bxv.y), fmaxf(bxv.z, bxv.w)));
        }
    }
    redmax[tid] = mymax;
    __syncthreads();
    for (int sgap = BSZ / 2; sgap > 0; sgap >>= 1) {
        if (tid < sgap) redmax[tid] = fmaxf(redmax[tid], redmax[tid + sgap]);
        __syncthreads();
    }
    if (tid == 0) maxb[b] = __fadd_rn(redmax[0], 1.0f);   // max(boxes)+1.0, exact rn like reference
}

// ---------------- Kernel 3: suppression bitmask, layout mask[b][word][row] ----------------
// 1008 blocks: IoU build is compute-heavy (~8M IoUs total) and must stay wide.
__global__ __launch_bounds__(256) void k_iou(
    const float4* __restrict__ topbox, const float* __restrict__ topcls,
    const float* __restrict__ maxb, unsigned long long* __restrict__ maskArr)
{
    __shared__ float4 sB[NM];
    __shared__ float sA[NM];
    const int b = blockIdx.y;
    const int tid = threadIdx.x;
    const float mp1 = maxb[b];
    for (int r = tid; r < NM; r += 256) {
        float4 f = topbox[b * NM + r];
        float off = __fmul_rn(topcls[b * NM + r], mp1);
        f.x = __fadd_rn(f.x, off); f.y = __fadd_rn(f.y, off);
        f.z = __fadd_rn(f.z, off); f.w = __fadd_rn(f.w, off);
        sB[r] = f;
        sA[r] = __fmul_rn(__fadd_rn(__fsub_rn(f.z, f.x), 1.0f),
                          __fadd_rn(__fsub_rn(f.w, f.y), 1.0f));
    }
    __syncthreads();
    int task = blockIdx.x * 256 + tid;
    if (task >= NM * 16) return;
    int w = task / NM, i = task - w * NM;
    float4 bi = sB[i]; float ai = sA[i];
    unsigned long long bits = 0ULL;
    int j0 = w << 6;
    int jstart = (j0 > i + 1) ? j0 : i + 1;
    int jend = (j0 + 64 < NM) ? j0 + 64 : NM;
    for (int j = jstart; j < jend; j++) {
        float4 bj = sB[j];
        float xx1 = fmaxf(bi.x, bj.x);
        float yy1 = fmaxf(bi.y, bj.y);
        float xx2 = fminf(bi.z, bj.z);
        float yy2 = fminf(bi.w, bj.w);
        float iw = fmaxf(__fsub_rn(xx2, xx1), 0.0f);
        float ih = fmaxf(__fsub_rn(yy2, yy1), 0.0f);
        float inter = __fmul_rn(iw, ih);
        float denom = __fsub_rn(__fadd_rn(ai, sA[j]), inter);
        float iou = inter / denom;
        if (iou > 0.6f) bits |= (1ULL << (j - j0));
    }
    maskArr[((size_t)b * 16 + w) * NM + i] = bits;
}

// ---------------- Kernel 4: LDS-resident word-serial sweep + masked output ----------------
__global__ __launch_bounds__(256) void k_nms_sweep(
    const unsigned long long* __restrict__ maskArr,
    const float* __restrict__ topscore, const float* __restrict__ topcls,
    const float4* __restrict__ topbox, float* __restrict__ out)
{
    __shared__ unsigned long long smask[16 * NM];   // 125 KB, [word][row]
    __shared__ unsigned long long lremv[16];
    const int b = blockIdx.x;
    const int tid = threadIdx.x;
    const int j = tid & 63, q = tid >> 6;
    const unsigned long long* gmask = maskArr + (size_t)b * (16 * NM);

    {
        const ulonglong2* src = (const ulonglong2*)gmask;
        ulonglong2* dst = (ulonglong2*)smask;
        for (int idx = tid; idx < 8 * NM; idx += 256) dst[idx] = src[idx];
    }
    if (tid < 16) lremv[tid] = 0ULL;
    __syncthreads();
    for (int r = tid; r < NM; r += 256) {
        float s = topscore[b * NM + r];
        if (!(s >= 0.05f)) atomicOr(&lremv[r >> 6], 1ULL << (r & 63));
    }

    for (int w = 0; w < 16; w++) {
        __syncthreads();   // prior word's cross-word atomics + seeds visible
        const int row = w * 64 + j;
        unsigned long long D = (row < NM) ? smask[w * NM + row] : 0ULL;
        unsigned int dlo = (unsigned int)D, dhi = (unsigned int)(D >> 32);
        unsigned long long sv = lremv[w];
        unsigned int slo = __builtin_amdgcn_readfirstlane((unsigned int)sv);
        unsigned int shi = __builtin_amdgcn_readfirstlane((unsigned int)(sv >> 32));
        unsigned long long s = ((unsigned long long)shi << 32) | slo;
#pragma unroll
        for (int bb = 0; bb < 64; bb++) {
            unsigned int rlo = __builtin_amdgcn_readlane(dlo, bb);
            unsigned int rhi = __builtin_amdgcn_readlane(dhi, bb);
            unsigned long long rowv = ((unsigned long long)rhi << 32) | rlo;
            unsigned long long t = s | rowv;
            s = ((s >> bb) & 1ULL) ? s : t;
        }
        if (tid == 0) lremv[w] = s;
        const unsigned long long kw = ~s;
        if ((kw >> j) & 1ULL) {
            for (int k = w + 1 + q; k < 16; k += 4) {
                unsigned long long v = (row < NM) ? smask[k * NM + row] : 0ULL;
                if (v) atomicOr(&lremv[k], v);
            }
        }
    }
    __syncthreads();

    for (int r = tid; r < NM; r += 256) {
        bool keep = !((lremv[r >> 6] >> (r & 63)) & 1ULL);
        float kf = keep ? 1.0f : 0.0f;
        out[b * NM + r] = topscore[b * NM + r] * kf;
        out[NB * NM + b * NM + r] = topcls[b * NM + r] * kf;
        float4 bx = topbox[b * NM + r];
        ((float4*)(out + 2 * NB * NM))[b * NM + r] = make_float4(bx.x * kf, bx.y * kf, bx.z * kf, bx.w * kf);
    }
}

extern "C" void kernel_launch(void* const* d_in, const int* in_sizes, int n_in,
                              void* d_out, int out_size, void* d_ws, size_t ws_size,
                              hipStream_t stream) {
    const float* cls3 = (const float*)d_in[0];
    const float* cnt3 = (const float*)d_in[1];
    const float* reg3 = (const float*)d_in[2];
    const float* cls4 = (const float*)d_in[3];
    const float* cnt4 = (const float*)d_in[4];
    const float* reg4 = (const float*)d_in[5];
    const float* cls5 = (const float*)d_in[6];
    const float* cnt5 = (const float*)d_in[7];
    const float* reg5 = (const float*)d_in[8];
    const float* cls6 = (const float*)d_in[9];
    const float* cnt6 = (const float*)d_in[10];
    const float* reg6 = (const float*)d_in[11];
    const float* cls7 = (const float*)d_in[12];
    const float* cnt7 = (const float*)d_in[13];
    const float* reg7 = (const float*)d_in[14];

    char* ws = (char*)d_ws;
    unsigned long long* keys   = (unsigned long long*)(ws + OFF_KEYS);
    float*              clsv   = (float*)(ws + OFF_CLSV);
    float*              topsc  = (float*)(ws + OFF_TOPSCORE);
    float*              topcl  = (float*)(ws + OFF_TOPCLS);
    float4*             topbx  = (float4*)(ws + OFF_TOPBOX);
    float*              maxbF  = (float*)(ws + OFF_MAXB);
    unsigned long long* maskA  = (unsigned long long*)(ws + OFF_MASK);

    dim3 g1(86, NB);   // 86*64 anchor-quads >= 5456
    k_score<<<g1, 256, 0, stream>>>(cls3, cnt3, cls4, cnt4, cls5, cnt5,
                                    cls6, cnt6, cls7, cnt7,
                                    keys, clsv);
    k_mid<<<dim3(NB), BSZ, 0, stream>>>(keys, clsv, reg3, reg4, reg5, reg6, reg7,
                                        topsc, topcl, topbx, maxbF);
    dim3 g4(63, NB);
    k_iou<<<g4, 256, 0, stream>>>(topbx, topcl, maxbF, maskA);
    k_nms_sweep<<<NB, 256, 0, stream>>>(maskA, topsc, topcl, topbx, (float*)d_out);
}